// Round 1
// baseline (1276.005 us; speedup 1.0000x reference)
//
#include <hip/hip_runtime.h>
#include <hip/hip_bf16.h>
#include <cstdint>
#include <cstddef>

// ---------------- kernels ----------------

__global__ void k_deg(const int* __restrict__ dst, int E, int* __restrict__ deg) {
    int e = blockIdx.x * blockDim.x + threadIdx.x;
    if (e < E) atomicAdd(&deg[dst[e]], 1);
}

__global__ void k_dinv(const int* __restrict__ deg, float* __restrict__ dinv, int N) {
    int i = blockIdx.x * blockDim.x + threadIdx.x;
    if (i < N) dinv[i] = rsqrtf((float)(deg[i] + 1));   // +1 = self loop; always >= 1
}

// Y[N,64] = X[N,64] @ W[64,64]; one wave per row, lane = output column.
__global__ void k_gemm64(const float* __restrict__ X, const float* __restrict__ W,
                         float* __restrict__ Y, int nrows) {
    __shared__ float sW[64 * 64];
    for (int i = threadIdx.x; i < 64 * 64; i += blockDim.x) sW[i] = W[i];
    __syncthreads();
    int lane = threadIdx.x & 63;
    int wid  = (blockIdx.x * blockDim.x + threadIdx.x) >> 6;
    int nw   = (gridDim.x * blockDim.x) >> 6;
    for (int row = wid; row < nrows; row += nw) {
        float xv = X[(size_t)row * 64 + lane];   // lane k holds x[row,k]
        float acc = 0.f;
#pragma unroll
        for (int k = 0; k < 64; ++k) {
            float xk = __shfl(xv, k, 64);
            acc = fmaf(xk, sW[k * 64 + lane], acc);
        }
        Y[(size_t)row * 64 + lane] = acc;
    }
}

// out[dst] += H[src] * dinv[src]*dinv[dst]; edges 0..E-1 from ei, then N self loops.
__global__ void k_scatter(const float* __restrict__ H, const float* __restrict__ dinv,
                          const int* __restrict__ ei, int E, int N,
                          float* __restrict__ out) {
    int lane = threadIdx.x & 63;
    int wid  = (blockIdx.x * blockDim.x + threadIdx.x) >> 6;
    int nw   = (gridDim.x * blockDim.x) >> 6;
    int total = E + N;
    for (int e = wid; e < total; e += nw) {
        int s, d;
        if (e < E) { s = ei[e]; d = ei[E + e]; }
        else       { s = e - E; d = s; }
        float nrm = dinv[s] * dinv[d];
        float v = H[(size_t)s * 64 + lane] * nrm;
        unsafeAtomicAdd(&out[(size_t)d * 64 + lane], v);
    }
}

// per-feature sum / sumsq into st[0..63] / st[64..127]
__global__ void k_stats(const float* __restrict__ H, int nrows, float* __restrict__ st) {
    int f   = threadIdx.x & 63;
    int grp = threadIdx.x >> 6;     // 0..3
    float s = 0.f, sq = 0.f;
    for (int row = blockIdx.x * 4 + grp; row < nrows; row += gridDim.x * 4) {
        float v = H[(size_t)row * 64 + f];
        s += v; sq += v * v;
    }
    __shared__ float ls[4][64], lq[4][64];
    ls[grp][f] = s; lq[grp][f] = sq;
    __syncthreads();
    if (grp == 0) {
        s  = ls[0][f] + ls[1][f] + ls[2][f] + ls[3][f];
        sq = lq[0][f] + lq[1][f] + lq[2][f] + lq[3][f];
        unsafeAtomicAdd(&st[f], s);
        unsafeAtomicAdd(&st[64 + f], sq);
    }
}

// sc[f] = g*rsqrt(var+eps); sc[64+f] = be - mean*scale   (conv bias cancels in BN)
__global__ void k_mkscale(const float* __restrict__ st, const float* __restrict__ g,
                          const float* __restrict__ be, int nrows, float* __restrict__ sc) {
    int f = threadIdx.x;
    if (f >= 64) return;
    float invn = 1.f / (float)nrows;
    float m   = st[f] * invn;
    float var = st[64 + f] * invn - m * m;
    float scale = g[f] * rsqrtf(var + 1e-5f);
    sc[f]      = scale;
    sc[64 + f] = be[f] - m * scale;
}

__global__ void k_bnrelu(const float4* __restrict__ in, const float* __restrict__ sc,
                         float4* __restrict__ out, int n4) {
    int i = blockIdx.x * blockDim.x + threadIdx.x;
    int stride = gridDim.x * blockDim.x;
    for (; i < n4; i += stride) {
        int f4 = (i & 15) << 2;
        float4 v = in[i];
        float4 r;
        r.x = fmaxf(fmaf(v.x, sc[f4 + 0], sc[64 + f4 + 0]), 0.f);
        r.y = fmaxf(fmaf(v.y, sc[f4 + 1], sc[64 + f4 + 1]), 0.f);
        r.z = fmaxf(fmaf(v.z, sc[f4 + 2], sc[64 + f4 + 2]), 0.f);
        r.w = fmaxf(fmaf(v.w, sc[f4 + 3], sc[64 + f4 + 3]), 0.f);
        out[i] = r;
    }
}

// fused: v = relu(bn2(agg)) + prev; psum[batch] += v; cnt[batch] += 1
__global__ void k_pool(const float* __restrict__ agg, const float* __restrict__ sc,
                       const float* __restrict__ prev, const int* __restrict__ batch,
                       float* __restrict__ psum, float* __restrict__ cnt, int nrows) {
    int lane = threadIdx.x & 63;
    int wid  = (blockIdx.x * blockDim.x + threadIdx.x) >> 6;
    int nw   = (gridDim.x * blockDim.x) >> 6;
    for (int row = wid; row < nrows; row += nw) {
        int b = batch[row];
        float v = fmaf(agg[(size_t)row * 64 + lane], sc[lane], sc[64 + lane]);
        v = fmaxf(v, 0.f) + prev[(size_t)row * 64 + lane];
        unsafeAtomicAdd(&psum[(size_t)b * 64 + lane], v);
        if (lane == 0) unsafeAtomicAdd(&cnt[b], 1.0f);
    }
}

// one thread per graph: mean-pool -> fc(64->32) relu -> fc(32->10) -> log_softmax
__global__ void k_head(const float* __restrict__ psum, const float* __restrict__ cnt,
                       const float* __restrict__ lw1, const float* __restrict__ lb1,
                       const float* __restrict__ lw2, const float* __restrict__ lb2,
                       float* __restrict__ out, int G) {
    int g = blockIdx.x * blockDim.x + threadIdx.x;
    if (g >= G) return;
    float inv = 1.f / fmaxf(cnt[g], 1.f);
    float p[64];
#pragma unroll
    for (int f = 0; f < 64; ++f) p[f] = psum[(size_t)g * 64 + f] * inv;
    float z[32];
#pragma unroll
    for (int j = 0; j < 32; ++j) {
        float a = lb1[j];
#pragma unroll
        for (int f = 0; f < 64; ++f) a = fmaf(p[f], lw1[f * 32 + j], a);
        z[j] = fmaxf(a, 0.f);
    }
    float lg[10];
    float mx = -1e30f;
#pragma unroll
    for (int c = 0; c < 10; ++c) {
        float a = lb2[c];
#pragma unroll
        for (int j = 0; j < 32; ++j) a = fmaf(z[j], lw2[j * 10 + c], a);
        lg[c] = a;
        mx = fmaxf(mx, a);
    }
    float se = 0.f;
#pragma unroll
    for (int c = 0; c < 10; ++c) se += expf(lg[c] - mx);
    float lse = logf(se) + mx;
#pragma unroll
    for (int c = 0; c < 10; ++c) out[(size_t)g * 10 + c] = lg[c] - lse;
}

// ---------------- launch ----------------

extern "C" void kernel_launch(void* const* d_in, const int* in_sizes, int n_in,
                              void* d_out, int out_size, void* d_ws, size_t ws_size,
                              hipStream_t stream) {
    const float* x    = (const float*)d_in[0];
    const int*   ei   = (const int*)d_in[1];     // [2,E]
    const int*   batch= (const int*)d_in[2];
    const float* W1   = (const float*)d_in[3];
    // d_in[4] = b1 : cancels in BN
    const float* g1   = (const float*)d_in[5];
    const float* be1  = (const float*)d_in[6];
    const float* W2   = (const float*)d_in[7];
    // d_in[8] = b2 : cancels in BN
    const float* g2   = (const float*)d_in[9];
    const float* be2  = (const float*)d_in[10];
    const float* lw1  = (const float*)d_in[11];
    const float* lb1  = (const float*)d_in[12];
    const float* lw2  = (const float*)d_in[13];
    const float* lb2  = (const float*)d_in[14];
    float* out = (float*)d_out;

    const int N = in_sizes[2];
    const int E = in_sizes[1] / 2;
    const int C = 10;
    const int G = out_size / C;

    char* w = (char*)d_ws;
    int*   deg  = (int*)w;      w += (size_t)N * 4;
    float* dinv = (float*)w;    w += (size_t)N * 4;
    float* bufA = (float*)w;    w += (size_t)N * 64 * 4;   // transform output
    float* bufB = (float*)w;    w += (size_t)N * 64 * 4;   // aggregation output
    float* bufC = (float*)w;    w += (size_t)N * 64 * 4;   // h1 after bn+relu (residual)
    float* st1  = (float*)w;    w += 128 * 4;
    float* sc1  = (float*)w;    w += 128 * 4;
    float* st2  = (float*)w;    w += 128 * 4;
    float* sc2  = (float*)w;    w += 128 * 4;
    float* psum = (float*)w;    w += (size_t)G * 64 * 4;
    float* cnt  = (float*)w;    w += (size_t)G * 4;

    hipMemsetAsync(deg,  0, (size_t)N * 4, stream);
    hipMemsetAsync(bufB, 0, (size_t)N * 64 * 4, stream);
    hipMemsetAsync(st1,  0, 128 * 4, stream);
    hipMemsetAsync(st2,  0, 128 * 4, stream);
    hipMemsetAsync(psum, 0, (size_t)G * 64 * 4, stream);
    hipMemsetAsync(cnt,  0, (size_t)G * 4, stream);

    k_deg <<<(E + 255) / 256, 256, 0, stream>>>(ei + E, E, deg);
    k_dinv<<<(N + 255) / 256, 256, 0, stream>>>(deg, dinv, N);

    // ---- layer 1 ----
    k_gemm64 <<<4096, 256, 0, stream>>>(x, W1, bufA, N);
    k_scatter<<<8192, 256, 0, stream>>>(bufA, dinv, ei, E, N, bufB);
    k_stats  <<<512, 256, 0, stream>>>(bufB, N, st1);
    k_mkscale<<<1, 64, 0, stream>>>(st1, g1, be1, N, sc1);
    k_bnrelu <<<4096, 256, 0, stream>>>((const float4*)bufB, sc1, (float4*)bufC, N * 16);

    // ---- layer 2 ----
    k_gemm64 <<<4096, 256, 0, stream>>>(bufC, W2, bufA, N);
    hipMemsetAsync(bufB, 0, (size_t)N * 64 * 4, stream);
    k_scatter<<<8192, 256, 0, stream>>>(bufA, dinv, ei, E, N, bufB);
    k_stats  <<<512, 256, 0, stream>>>(bufB, N, st2);
    k_mkscale<<<1, 64, 0, stream>>>(st2, g2, be2, N, sc2);

    // fused bn2+relu+residual+pool
    k_pool<<<8192, 256, 0, stream>>>(bufB, sc2, bufC, batch, psum, cnt, N);

    // head
    k_head<<<(G + 255) / 256, 256, 0, stream>>>(psum, cnt, lw1, lb1, lw2, lb2, out, G);
}

// Round 2
// 754.636 us; speedup vs baseline: 1.6909x; 1.6909x over previous
//
#include <hip/hip_runtime.h>
#include <hip/hip_bf16.h>
#include <cstdint>
#include <cstddef>

// ---------------- graph preprocessing ----------------

__global__ void k_deg(const int* __restrict__ dst, int E, int* __restrict__ deg) {
    int e = blockIdx.x * blockDim.x + threadIdx.x;
    if (e < E) atomicAdd(&deg[dst[e]], 1);
}

__global__ void k_dinv(const int* __restrict__ deg, float* __restrict__ dinv, int N) {
    int i = blockIdx.x * blockDim.x + threadIdx.x;
    if (i < N) dinv[i] = rsqrtf((float)(deg[i] + 1));   // +1 = self loop
}

// exclusive scan of deg, blockwise
__global__ void k_scan1(const int* __restrict__ deg, int* __restrict__ offs,
                        int* __restrict__ bsum, int N) {
    __shared__ int sh[256];
    int i = blockIdx.x * 256 + threadIdx.x;
    int v = (i < N) ? deg[i] : 0;
    sh[threadIdx.x] = v;
    __syncthreads();
#pragma unroll
    for (int o = 1; o < 256; o <<= 1) {
        int t = (threadIdx.x >= o) ? sh[threadIdx.x - o] : 0;
        __syncthreads();
        sh[threadIdx.x] += t;
        __syncthreads();
    }
    if (i < N) offs[i] = sh[threadIdx.x] - v;           // exclusive within block
    if (threadIdx.x == 255) bsum[blockIdx.x] = sh[255];
}

__global__ void k_scan2(int* __restrict__ bsum, int nb) {
    __shared__ int sh[1024];
    int t = threadIdx.x;
    sh[t] = (t < nb) ? bsum[t] : 0;
    __syncthreads();
    if (t == 0) {
        int acc = 0;
        for (int i = 0; i < nb; ++i) { int x = sh[i]; sh[i] = acc; acc += x; }
    }
    __syncthreads();
    if (t < nb) bsum[t] = sh[t];
}

__global__ void k_scan3(int* __restrict__ offs, const int* __restrict__ bsum, int N) {
    int i = blockIdx.x * 256 + threadIdx.x;
    if (i < N) offs[i] += bsum[blockIdx.x];
}

// after fill, offs[d] points at end of d's adjacency slot; start = offs[d]-deg[d]
__global__ void k_fill(const int* __restrict__ ei, int E,
                       int* __restrict__ offs, int* __restrict__ adj) {
    int e = blockIdx.x * blockDim.x + threadIdx.x;
    if (e >= E) return;
    int s = ei[e], d = ei[E + e];
    int pos = atomicAdd(&offs[d], 1);
    adj[pos] = s;
}

// ---------------- compute kernels ----------------

// Y[row] = (BN? relu(bn(X[row])) : X[row]) @ W * dinv[row]
template <bool BN>
__global__ void k_gemm64(const float* __restrict__ X, const float* __restrict__ W,
                         const float* __restrict__ dinv, const float* __restrict__ sc,
                         float* __restrict__ Y, int nrows) {
    __shared__ float sW[64 * 64];
    for (int i = threadIdx.x; i < 64 * 64; i += blockDim.x) sW[i] = W[i];
    __syncthreads();
    int lane = threadIdx.x & 63;
    int wid  = (blockIdx.x * blockDim.x + threadIdx.x) >> 6;
    int nw   = (gridDim.x * blockDim.x) >> 6;
    for (int row = wid; row < nrows; row += nw) {
        float xv = X[(size_t)row * 64 + lane];
        if (BN) xv = fmaxf(fmaf(xv, sc[lane], sc[64 + lane]), 0.f);
        float acc = 0.f;
#pragma unroll
        for (int k = 0; k < 64; ++k) {
            float xk = __shfl(xv, k, 64);
            acc = fmaf(xk, sW[k * 64 + lane], acc);
        }
        Y[(size_t)row * 64 + lane] = acc * dinv[row];
    }
}

// out[d] = dinv[d] * (HA[d] + sum_{s in adj(d)} HA[s]);  HA already has dinv[s] folded in.
// fused per-feature sum/sumsq accumulation into st[0..63]/st[64..127].
__global__ void k_gather(const float* __restrict__ HA, const int* __restrict__ deg,
                         const int* __restrict__ offs, const int* __restrict__ adj,
                         const float* __restrict__ dinv, float* __restrict__ out,
                         float* __restrict__ st, int N) {
    int lane = threadIdx.x & 63;
    int wid  = (blockIdx.x * blockDim.x + threadIdx.x) >> 6;
    int nw   = (gridDim.x * blockDim.x) >> 6;
    float s_ = 0.f, sq_ = 0.f;
    for (int row = wid; row < N; row += nw) {
        int end   = offs[row];
        int start = end - deg[row];
        float acc = HA[(size_t)row * 64 + lane];       // self loop
        for (int base = start; base < end; base += 64) {
            int m = min(64, end - base);
            int a = (base + lane < end) ? adj[base + lane] : 0;
            for (int k = 0; k < m; ++k) {
                int s = __shfl(a, k, 64);
                acc += HA[(size_t)s * 64 + lane];
            }
        }
        float v = acc * dinv[row];
        out[(size_t)row * 64 + lane] = v;
        s_ += v; sq_ += v * v;
    }
    __shared__ float ls[4][64], lq[4][64];
    int grp = threadIdx.x >> 6;
    ls[grp][lane] = s_; lq[grp][lane] = sq_;
    __syncthreads();
    if (grp == 0) {
        s_  = ls[0][lane] + ls[1][lane] + ls[2][lane] + ls[3][lane];
        sq_ = lq[0][lane] + lq[1][lane] + lq[2][lane] + lq[3][lane];
        unsafeAtomicAdd(&st[lane], s_);
        unsafeAtomicAdd(&st[64 + lane], sq_);
    }
}

// sc[f]=g*rsqrt(var+eps); sc[64+f]=be-mean*scale (conv bias cancels in BN)
__global__ void k_mkscale(const float* __restrict__ st, const float* __restrict__ g,
                          const float* __restrict__ be, int nrows, float* __restrict__ sc) {
    int f = threadIdx.x;
    if (f >= 64) return;
    float invn = 1.f / (float)nrows;
    float m   = st[f] * invn;
    float var = st[64 + f] * invn - m * m;
    float scale = g[f] * rsqrtf(var + 1e-5f);
    sc[f]      = scale;
    sc[64 + f] = be[f] - m * scale;
}

// segmented pool: one wave per 64 contiguous rows (batch is sorted).
// v = relu(bn2(r2)) + relu(bn1(r1)); psum[batch] += v with one atomic per segment.
__global__ void k_pool(const float* __restrict__ r2, const float* __restrict__ sc2,
                       const float* __restrict__ r1, const float* __restrict__ sc1,
                       const int* __restrict__ batch, float* __restrict__ psum, int N) {
    int lane = threadIdx.x & 63;
    int wv   = (blockIdx.x * blockDim.x + threadIdx.x) >> 6;
    int r0   = wv * 64;
    if (r0 >= N) return;
    int rend = min(r0 + 64, N);
    int bv = (r0 + lane < N) ? batch[r0 + lane] : -1;
    float s2a = sc2[lane], s2b = sc2[64 + lane];
    float s1a = sc1[lane], s1b = sc1[64 + lane];
    float acc = 0.f;
    int cur = __shfl(bv, 0, 64);
    for (int r = r0; r < rend; ++r) {
        int b = __shfl(bv, r - r0, 64);
        if (b != cur) {
            unsafeAtomicAdd(&psum[(size_t)cur * 64 + lane], acc);
            acc = 0.f; cur = b;
        }
        float v2 = fmaxf(fmaf(r2[(size_t)r * 64 + lane], s2a, s2b), 0.f);
        float v1 = fmaxf(fmaf(r1[(size_t)r * 64 + lane], s1a, s1b), 0.f);
        acc += v1 + v2;
    }
    unsafeAtomicAdd(&psum[(size_t)cur * 64 + lane], acc);
}

// cnt[g] via binary search over sorted batch
__global__ void k_cnt(const int* __restrict__ batch, int N, float* __restrict__ cnt, int G) {
    int g = blockIdx.x * blockDim.x + threadIdx.x;
    if (g >= G) return;
    int lo = 0, hi = N;
    while (lo < hi) { int mid = (lo + hi) >> 1; if (batch[mid] < g) lo = mid + 1; else hi = mid; }
    int lb = lo;
    hi = N;
    while (lo < hi) { int mid = (lo + hi) >> 1; if (batch[mid] < g + 1) lo = mid + 1; else hi = mid; }
    cnt[g] = (float)(lo - lb);
}

// one thread per graph: mean-pool -> fc(64->32) relu -> fc(32->10) -> log_softmax
__global__ void k_head(const float* __restrict__ psum, const float* __restrict__ cnt,
                       const float* __restrict__ lw1, const float* __restrict__ lb1,
                       const float* __restrict__ lw2, const float* __restrict__ lb2,
                       float* __restrict__ out, int G) {
    int g = blockIdx.x * blockDim.x + threadIdx.x;
    if (g >= G) return;
    float inv = 1.f / fmaxf(cnt[g], 1.f);
    float p[64];
#pragma unroll
    for (int f = 0; f < 64; ++f) p[f] = psum[(size_t)g * 64 + f] * inv;
    float z[32];
#pragma unroll
    for (int j = 0; j < 32; ++j) {
        float a = lb1[j];
#pragma unroll
        for (int f = 0; f < 64; ++f) a = fmaf(p[f], lw1[f * 32 + j], a);
        z[j] = fmaxf(a, 0.f);
    }
    float lg[10];
    float mx = -1e30f;
#pragma unroll
    for (int c = 0; c < 10; ++c) {
        float a = lb2[c];
#pragma unroll
        for (int j = 0; j < 32; ++j) a = fmaf(z[j], lw2[j * 10 + c], a);
        lg[c] = a;
        mx = fmaxf(mx, a);
    }
    float se = 0.f;
#pragma unroll
    for (int c = 0; c < 10; ++c) se += expf(lg[c] - mx);
    float lse = logf(se) + mx;
#pragma unroll
    for (int c = 0; c < 10; ++c) out[(size_t)g * 10 + c] = lg[c] - lse;
}

// ---------------- launch ----------------

extern "C" void kernel_launch(void* const* d_in, const int* in_sizes, int n_in,
                              void* d_out, int out_size, void* d_ws, size_t ws_size,
                              hipStream_t stream) {
    const float* x    = (const float*)d_in[0];
    const int*   ei   = (const int*)d_in[1];     // [2,E]
    const int*   batch= (const int*)d_in[2];
    const float* W1   = (const float*)d_in[3];
    // d_in[4] = b1 : cancels in BN
    const float* g1   = (const float*)d_in[5];
    const float* be1  = (const float*)d_in[6];
    const float* W2   = (const float*)d_in[7];
    // d_in[8] = b2 : cancels in BN
    const float* g2   = (const float*)d_in[9];
    const float* be2  = (const float*)d_in[10];
    const float* lw1  = (const float*)d_in[11];
    const float* lb1  = (const float*)d_in[12];
    const float* lw2  = (const float*)d_in[13];
    const float* lb2  = (const float*)d_in[14];
    float* out = (float*)d_out;

    const int N = in_sizes[2];
    const int E = in_sizes[1] / 2;
    const int C = 10;
    const int G = out_size / C;
    const int NB = (N + 255) / 256;              // scan blocks (<=1024)

    char* w = (char*)d_ws;
    int*   deg  = (int*)w;      w += (size_t)N * 4;
    int*   offs = (int*)w;      w += (size_t)N * 4;
    int*   adj  = (int*)w;      w += (size_t)E * 4;
    int*   bsum = (int*)w;      w += 1024 * 4;
    float* dinv = (float*)w;    w += (size_t)N * 4;
    float* bufA = (float*)w;    w += (size_t)N * 64 * 4;   // transform output (dinv folded)
    float* bufB1= (float*)w;    w += (size_t)N * 64 * 4;   // raw agg layer 1
    float* bufB2= (float*)w;    w += (size_t)N * 64 * 4;   // raw agg layer 2
    float* st1  = (float*)w;    w += 128 * 4;
    float* sc1  = (float*)w;    w += 128 * 4;
    float* st2  = (float*)w;    w += 128 * 4;
    float* sc2  = (float*)w;    w += 128 * 4;
    float* psum = (float*)w;    w += (size_t)G * 64 * 4;
    float* cnt  = (float*)w;    w += (size_t)G * 4;

    hipMemsetAsync(deg,  0, (size_t)N * 4, stream);
    hipMemsetAsync(st1,  0, 128 * 4, stream);
    hipMemsetAsync(st2,  0, 128 * 4, stream);
    hipMemsetAsync(psum, 0, (size_t)G * 64 * 4, stream);

    // graph preprocessing: deg -> dinv, CSR(offs, adj)
    k_deg  <<<(E + 255) / 256, 256, 0, stream>>>(ei + E, E, deg);
    k_dinv <<<(N + 255) / 256, 256, 0, stream>>>(deg, dinv, N);
    k_scan1<<<NB, 256, 0, stream>>>(deg, offs, bsum, N);
    k_scan2<<<1, 1024, 0, stream>>>(bsum, NB);
    k_scan3<<<NB, 256, 0, stream>>>(offs, bsum, N);
    k_fill <<<(E + 255) / 256, 256, 0, stream>>>(ei, E, offs, adj);
    k_cnt  <<<(G + 255) / 256, 256, 0, stream>>>(batch, N, cnt, G);

    // ---- layer 1 ----
    k_gemm64<false><<<2048, 256, 0, stream>>>(x, W1, dinv, nullptr, bufA, N);
    k_gather<<<2048, 256, 0, stream>>>(bufA, deg, offs, adj, dinv, bufB1, st1, N);
    k_mkscale<<<1, 64, 0, stream>>>(st1, g1, be1, N, sc1);

    // ---- layer 2 (bn1+relu fused into gemm load) ----
    k_gemm64<true><<<2048, 256, 0, stream>>>(bufB1, W2, dinv, sc1, bufA, N);
    k_gather<<<2048, 256, 0, stream>>>(bufA, deg, offs, adj, dinv, bufB2, st2, N);
    k_mkscale<<<1, 64, 0, stream>>>(st2, g2, be2, N, sc2);

    // fused bn2+relu + recomputed bn1+relu residual + segmented mean-pool
    {
        int waves = (N + 63) / 64;
        int blocks = (waves + 3) / 4;
        k_pool<<<blocks, 256, 0, stream>>>(bufB2, sc2, bufB1, sc1, batch, psum, N);
    }

    // head
    k_head<<<(G + 255) / 256, 256, 0, stream>>>(psum, cnt, lw1, lb1, lw2, lb2, out, G);
}

// Round 3
// 604.420 us; speedup vs baseline: 2.1111x; 1.2485x over previous
//
#include <hip/hip_runtime.h>
#include <hip/hip_bf16.h>
#include <cstdint>
#include <cstddef>

// ---------------- graph preprocessing ----------------

__global__ void k_deg(const int* __restrict__ dst, int E, int* __restrict__ deg) {
    int e = blockIdx.x * blockDim.x + threadIdx.x;
    if (e < E) atomicAdd(&deg[dst[e]], 1);
}

__global__ void k_dinv(const int* __restrict__ deg, float* __restrict__ dinv, int N) {
    int i = blockIdx.x * blockDim.x + threadIdx.x;
    if (i < N) dinv[i] = rsqrtf((float)(deg[i] + 1));   // +1 = self loop
}

// exclusive scan of deg, blockwise
__global__ void k_scan1(const int* __restrict__ deg, int* __restrict__ offs,
                        int* __restrict__ bsum, int N) {
    __shared__ int sh[256];
    int i = blockIdx.x * 256 + threadIdx.x;
    int v = (i < N) ? deg[i] : 0;
    sh[threadIdx.x] = v;
    __syncthreads();
#pragma unroll
    for (int o = 1; o < 256; o <<= 1) {
        int t = (threadIdx.x >= o) ? sh[threadIdx.x - o] : 0;
        __syncthreads();
        sh[threadIdx.x] += t;
        __syncthreads();
    }
    if (i < N) offs[i] = sh[threadIdx.x] - v;           // exclusive within block
    if (threadIdx.x == 255) bsum[blockIdx.x] = sh[255];
}

__global__ void k_scan2(int* __restrict__ bsum, int nb) {
    __shared__ int sh[1024];
    int t = threadIdx.x;
    sh[t] = (t < nb) ? bsum[t] : 0;
    __syncthreads();
    if (t == 0) {
        int acc = 0;
        for (int i = 0; i < nb; ++i) { int x = sh[i]; sh[i] = acc; acc += x; }
    }
    __syncthreads();
    if (t < nb) bsum[t] = sh[t];
}

__global__ void k_scan3(int* __restrict__ offs, const int* __restrict__ bsum, int N) {
    int i = blockIdx.x * 256 + threadIdx.x;
    if (i < N) offs[i] += bsum[blockIdx.x];
}

// after fill, offs[d] points at end of d's adjacency slot; start = offs[d]-deg[d]
__global__ void k_fill(const int* __restrict__ ei, int E,
                       int* __restrict__ offs, int* __restrict__ adj) {
    int e = blockIdx.x * blockDim.x + threadIdx.x;
    if (e >= E) return;
    int s = ei[e], d = ei[E + e];
    int pos = atomicAdd(&offs[d], 1);
    adj[pos] = s;
}

// ---------------- compute kernels ----------------

// Y[row] = X[row] @ W * dinv[row].
// One wave per row: x-row read via scalar loads (wave-uniform address),
// lane j holds W[:,j] in 64 VGPRs. Inner loop = 64 pure VALU FMAs, no LDS.
__global__ __launch_bounds__(256) void k_gemm64(
        const float* __restrict__ X, const float* __restrict__ W,
        const float* __restrict__ dinv, float* __restrict__ Y, int nrows) {
    int lane = threadIdx.x & 63;
    int wid  = (blockIdx.x * blockDim.x + threadIdx.x) >> 6;
    int nw   = (gridDim.x * blockDim.x) >> 6;
    float w[64];
#pragma unroll
    for (int k = 0; k < 64; ++k) w[k] = W[k * 64 + lane];
    for (int row = wid; row < nrows; row += nw) {
        int ur = __builtin_amdgcn_readfirstlane(row);
        const float* xr = X + (size_t)ur * 64;
        float a0 = 0.f, a1 = 0.f, a2 = 0.f, a3 = 0.f;
#pragma unroll
        for (int k = 0; k < 64; k += 4) {
            a0 = fmaf(xr[k + 0], w[k + 0], a0);
            a1 = fmaf(xr[k + 1], w[k + 1], a1);
            a2 = fmaf(xr[k + 2], w[k + 2], a2);
            a3 = fmaf(xr[k + 3], w[k + 3], a3);
        }
        float acc = (a0 + a1) + (a2 + a3);
        Y[(size_t)ur * 64 + lane] = acc * dinv[ur];
    }
}

// out[d] = dinv[d] * (HA[d] + sum_{s in adj(d)} HA[s]);  HA has dinv[s] folded in.
// Adjacency ids fetched via scalar loads (8 at a time), 4 independent accumulators.
// Fused per-feature sum/sumsq into st[0..63]/st[64..127].
__global__ __launch_bounds__(256) void k_gather(
        const float* __restrict__ HA, const int* __restrict__ deg,
        const int* __restrict__ offs, const int* __restrict__ adj,
        const float* __restrict__ dinv, float* __restrict__ out,
        float* __restrict__ st, int N) {
    int lane = threadIdx.x & 63;
    int wid  = (blockIdx.x * blockDim.x + threadIdx.x) >> 6;
    int nw   = (gridDim.x * blockDim.x) >> 6;
    float s_ = 0.f, sq_ = 0.f;
    for (int row = wid; row < N; row += nw) {
        int ur    = __builtin_amdgcn_readfirstlane(row);
        int end   = offs[ur];
        int start = end - deg[ur];
        float a0 = HA[(size_t)ur * 64 + lane];     // self loop
        float a1 = 0.f, a2 = 0.f, a3 = 0.f;
        int base = start;
        for (; base + 8 <= end; base += 8) {
            const int* ap = adj + base;
            int e0 = ap[0], e1 = ap[1], e2 = ap[2], e3 = ap[3];
            int e4 = ap[4], e5 = ap[5], e6 = ap[6], e7 = ap[7];
            a0 += HA[(size_t)e0 * 64 + lane];
            a1 += HA[(size_t)e1 * 64 + lane];
            a2 += HA[(size_t)e2 * 64 + lane];
            a3 += HA[(size_t)e3 * 64 + lane];
            a0 += HA[(size_t)e4 * 64 + lane];
            a1 += HA[(size_t)e5 * 64 + lane];
            a2 += HA[(size_t)e6 * 64 + lane];
            a3 += HA[(size_t)e7 * 64 + lane];
        }
        for (; base < end; ++base) {
            int e = adj[base];
            a0 += HA[(size_t)e * 64 + lane];
        }
        float v = ((a0 + a1) + (a2 + a3)) * dinv[ur];
        out[(size_t)ur * 64 + lane] = v;
        s_ += v; sq_ += v * v;
    }
    __shared__ float ls[4][64], lq[4][64];
    int grp = threadIdx.x >> 6;
    ls[grp][lane] = s_; lq[grp][lane] = sq_;
    __syncthreads();
    if (grp == 0) {
        s_  = ls[0][lane] + ls[1][lane] + ls[2][lane] + ls[3][lane];
        sq_ = lq[0][lane] + lq[1][lane] + lq[2][lane] + lq[3][lane];
        unsafeAtomicAdd(&st[lane], s_);
        unsafeAtomicAdd(&st[64 + lane], sq_);
    }
}

// sc[f]=g*rsqrt(var+eps); sc[64+f]=be-mean*scale (conv bias cancels in BN)
__global__ void k_mkscale(const float* __restrict__ st, const float* __restrict__ g,
                          const float* __restrict__ be, int nrows, float* __restrict__ sc) {
    int f = threadIdx.x;
    if (f >= 64) return;
    float invn = 1.f / (float)nrows;
    float m   = st[f] * invn;
    float var = st[64 + f] * invn - m * m;
    float scale = g[f] * rsqrtf(var + 1e-5f);
    sc[f]      = scale;
    sc[64 + f] = be[f] - m * scale;
}

// elementwise: out = relu(in*scA + scB), float4
__global__ void k_bnrelu(const float4* __restrict__ in, const float* __restrict__ sc,
                         float4* __restrict__ out, int n4) {
    int i = blockIdx.x * blockDim.x + threadIdx.x;
    int stride = gridDim.x * blockDim.x;
    for (; i < n4; i += stride) {
        int f4 = (i & 15) << 2;
        float4 v = in[i];
        float4 r;
        r.x = fmaxf(fmaf(v.x, sc[f4 + 0], sc[64 + f4 + 0]), 0.f);
        r.y = fmaxf(fmaf(v.y, sc[f4 + 1], sc[64 + f4 + 1]), 0.f);
        r.z = fmaxf(fmaf(v.z, sc[f4 + 2], sc[64 + f4 + 2]), 0.f);
        r.w = fmaxf(fmaf(v.w, sc[f4 + 3], sc[64 + f4 + 3]), 0.f);
        out[i] = r;
    }
}

// segmented pool: one wave per 64 contiguous rows (batch is sorted).
// v = relu(bn2(r2)) + c1; psum[batch] += v with one atomic per segment.
__global__ void k_pool(const float* __restrict__ r2, const float* __restrict__ sc2,
                       const float* __restrict__ c1, const int* __restrict__ batch,
                       float* __restrict__ psum, int N) {
    int lane = threadIdx.x & 63;
    int wv   = (blockIdx.x * blockDim.x + threadIdx.x) >> 6;
    int r0   = wv * 64;
    if (r0 >= N) return;
    int rend = min(r0 + 64, N);
    int bv = (r0 + lane < N) ? batch[r0 + lane] : -1;
    float s2a = sc2[lane], s2b = sc2[64 + lane];
    float acc = 0.f;
    int cur = __shfl(bv, 0, 64);
    for (int r = r0; r < rend; ++r) {
        int b = __shfl(bv, r - r0, 64);
        if (b != cur) {
            unsafeAtomicAdd(&psum[(size_t)cur * 64 + lane], acc);
            acc = 0.f; cur = b;
        }
        float v2 = fmaxf(fmaf(r2[(size_t)r * 64 + lane], s2a, s2b), 0.f);
        acc += v2 + c1[(size_t)r * 64 + lane];
    }
    unsafeAtomicAdd(&psum[(size_t)cur * 64 + lane], acc);
}

// cnt[g] via binary search over sorted batch
__global__ void k_cnt(const int* __restrict__ batch, int N, float* __restrict__ cnt, int G) {
    int g = blockIdx.x * blockDim.x + threadIdx.x;
    if (g >= G) return;
    int lo = 0, hi = N;
    while (lo < hi) { int mid = (lo + hi) >> 1; if (batch[mid] < g) lo = mid + 1; else hi = mid; }
    int lb = lo;
    hi = N;
    while (lo < hi) { int mid = (lo + hi) >> 1; if (batch[mid] < g + 1) lo = mid + 1; else hi = mid; }
    cnt[g] = (float)(lo - lb);
}

// one thread per graph: mean-pool -> fc(64->32) relu -> fc(32->10) -> log_softmax
__global__ void k_head(const float* __restrict__ psum, const float* __restrict__ cnt,
                       const float* __restrict__ lw1, const float* __restrict__ lb1,
                       const float* __restrict__ lw2, const float* __restrict__ lb2,
                       float* __restrict__ out, int G) {
    int g = blockIdx.x * blockDim.x + threadIdx.x;
    if (g >= G) return;
    float inv = 1.f / fmaxf(cnt[g], 1.f);
    float p[64];
#pragma unroll
    for (int f = 0; f < 64; ++f) p[f] = psum[(size_t)g * 64 + f] * inv;
    float z[32];
#pragma unroll
    for (int j = 0; j < 32; ++j) {
        float a = lb1[j];
#pragma unroll
        for (int f = 0; f < 64; ++f) a = fmaf(p[f], lw1[f * 32 + j], a);
        z[j] = fmaxf(a, 0.f);
    }
    float lg[10];
    float mx = -1e30f;
#pragma unroll
    for (int c = 0; c < 10; ++c) {
        float a = lb2[c];
#pragma unroll
        for (int j = 0; j < 32; ++j) a = fmaf(z[j], lw2[j * 10 + c], a);
        lg[c] = a;
        mx = fmaxf(mx, a);
    }
    float se = 0.f;
#pragma unroll
    for (int c = 0; c < 10; ++c) se += expf(lg[c] - mx);
    float lse = logf(se) + mx;
#pragma unroll
    for (int c = 0; c < 10; ++c) out[(size_t)g * 10 + c] = lg[c] - lse;
}

// ---------------- launch ----------------

extern "C" void kernel_launch(void* const* d_in, const int* in_sizes, int n_in,
                              void* d_out, int out_size, void* d_ws, size_t ws_size,
                              hipStream_t stream) {
    const float* x    = (const float*)d_in[0];
    const int*   ei   = (const int*)d_in[1];     // [2,E]
    const int*   batch= (const int*)d_in[2];
    const float* W1   = (const float*)d_in[3];
    // d_in[4] = b1 : cancels in BN
    const float* g1   = (const float*)d_in[5];
    const float* be1  = (const float*)d_in[6];
    const float* W2   = (const float*)d_in[7];
    // d_in[8] = b2 : cancels in BN
    const float* g2   = (const float*)d_in[9];
    const float* be2  = (const float*)d_in[10];
    const float* lw1  = (const float*)d_in[11];
    const float* lb1  = (const float*)d_in[12];
    const float* lw2  = (const float*)d_in[13];
    const float* lb2  = (const float*)d_in[14];
    float* out = (float*)d_out;

    const int N = in_sizes[2];
    const int E = in_sizes[1] / 2;
    const int C = 10;
    const int G = out_size / C;
    const int NB = (N + 255) / 256;              // scan blocks (<=1024)

    char* w = (char*)d_ws;
    int*   deg  = (int*)w;      w += (size_t)N * 4;
    int*   offs = (int*)w;      w += (size_t)N * 4;
    int*   adj  = (int*)w;      w += (size_t)(E + 8) * 4;   // +8 pad for scalar prefetch
    int*   bsum = (int*)w;      w += 1024 * 4;
    float* dinv = (float*)w;    w += (size_t)N * 4;
    float* T1   = (float*)w;    w += (size_t)N * 64 * 4;   // transform1 -> then bnrelu'd h1
    float* R1   = (float*)w;    w += (size_t)N * 64 * 4;   // raw agg1 -> then transform2
    float* B2   = (float*)w;    w += (size_t)N * 64 * 4;   // raw agg2
    float* st1  = (float*)w;    w += 128 * 4;
    float* sc1  = (float*)w;    w += 128 * 4;
    float* st2  = (float*)w;    w += 128 * 4;
    float* sc2  = (float*)w;    w += 128 * 4;
    float* psum = (float*)w;    w += (size_t)G * 64 * 4;
    float* cnt  = (float*)w;    w += (size_t)G * 4;

    hipMemsetAsync(deg,  0, (size_t)N * 4, stream);
    hipMemsetAsync(st1,  0, 128 * 4, stream);
    hipMemsetAsync(st2,  0, 128 * 4, stream);
    hipMemsetAsync(psum, 0, (size_t)G * 64 * 4, stream);

    // graph preprocessing: deg -> dinv, CSR(offs, adj)
    k_deg  <<<(E + 255) / 256, 256, 0, stream>>>(ei + E, E, deg);
    k_dinv <<<(N + 255) / 256, 256, 0, stream>>>(deg, dinv, N);
    k_scan1<<<NB, 256, 0, stream>>>(deg, offs, bsum, N);
    k_scan2<<<1, 1024, 0, stream>>>(bsum, NB);
    k_scan3<<<NB, 256, 0, stream>>>(offs, bsum, N);
    k_fill <<<(E + 255) / 256, 256, 0, stream>>>(ei, E, offs, adj);
    k_cnt  <<<(G + 255) / 256, 256, 0, stream>>>(batch, N, cnt, G);

    // ---- layer 1 ----
    k_gemm64 <<<2048, 256, 0, stream>>>(x, W1, dinv, T1, N);
    k_gather <<<2048, 256, 0, stream>>>(T1, deg, offs, adj, dinv, R1, st1, N);
    k_mkscale<<<1, 64, 0, stream>>>(st1, g1, be1, N, sc1);
    k_bnrelu <<<2048, 256, 0, stream>>>((const float4*)R1, sc1, (float4*)T1, N * 16);

    // ---- layer 2 ----
    k_gemm64 <<<2048, 256, 0, stream>>>(T1, W2, dinv, R1, N);
    k_gather <<<2048, 256, 0, stream>>>(R1, deg, offs, adj, dinv, B2, st2, N);
    k_mkscale<<<1, 64, 0, stream>>>(st2, g2, be2, N, sc2);

    // fused bn2+relu + residual(c1) + segmented mean-pool
    {
        int waves = (N + 63) / 64;
        int blocks = (waves + 3) / 4;
        k_pool<<<blocks, 256, 0, stream>>>(B2, sc2, T1, batch, psum, N);
    }

    // head
    k_head<<<(G + 255) / 256, 256, 0, stream>>>(psum, cnt, lw1, lb1, lw2, lb2, out, G);
}